// Round 9
// baseline (356.395 us; speedup 1.0000x reference)
//
#include <hip/hip_runtime.h>

#define HDIM 128
#define GCOUNT 64
#define CHUNK 2048

// ---- bf16 helpers (manual, RNE) ----
__device__ __forceinline__ float bfl(unsigned u) { return __uint_as_float(u << 16); }
__device__ __forceinline__ unsigned short f2bf(float f) {
  unsigned u = __float_as_uint(f);
  unsigned r = (u + 0x7fffu + ((u >> 16) & 1u)) >> 16;
  return (unsigned short)r;
}
__device__ __forceinline__ unsigned pk2(float a, float b) {
  return (unsigned)f2bf(a) | ((unsigned)f2bf(b) << 16);
}

typedef __attribute__((ext_vector_type(8))) short short8;
typedef __attribute__((ext_vector_type(4))) float f32x4;

__device__ __forceinline__ unsigned qb(float v, float rinv) {
  int q = (int)rintf(v * rinv);
  return (unsigned)(q & 0xff);
}

// ------- mega1: weight transpose->fragment order | zero pooled/gcnt/sentinels |
//         coarse hist | prescale int8 -------
// Weight fragment layout (ushort index):
//   di = ((kb*8 + nt)*64 + quad*16 + m)*8 + e
// k = kb*32 + quad*8 + e (input feature), nn = nt*16 + m (output feature).
// uint4 index = (kb*8+nt)*64 + lane; one kb-plane = 512 uint4 = 8KB chunk.

__global__ void mega1(const float* __restrict__ W0, const float* __restrict__ W1,
                      const float* __restrict__ W2,
                      unsigned short* __restrict__ h0, unsigned short* __restrict__ l0,
                      unsigned short* __restrict__ h1, unsigned short* __restrict__ l1,
                      unsigned short* __restrict__ h2, unsigned short* __restrict__ l2,
                      float* __restrict__ pooled, float* __restrict__ gcnt, int pz,
                      const int* __restrict__ dst, int E, int G, int NB1,
                      int* __restrict__ gcount,
                      const float* __restrict__ x, uint2* __restrict__ S,
                      uint2* __restrict__ Sb, float* __restrict__ csaP,
                      float* __restrict__ csbP,
                      float* __restrict__ cs_base, int n) {
  __shared__ int hist[512];
  int b = blockIdx.x, t = threadIdx.x;
  if (b < 192) {
    int w = b >> 6;
    int idx = (b & 63) * 256 + t;
    const float* W = (w == 0) ? W0 : (w == 1) ? W1 : W2;
    unsigned short* hi = (w == 0) ? h0 : (w == 1) ? h1 : h2;
    unsigned short* lo = (w == 0) ? l0 : (w == 1) ? l1 : l2;
    int k = idx >> 7, nn = idx & 127;
    float wv = W[idx];
    unsigned short h = f2bf(wv);
    float hf = __uint_as_float((unsigned)h << 16);
    unsigned short l = f2bf(wv - hf);
    int kb = k >> 5, quad = (k >> 3) & 3, e = k & 7;
    int nt = nn >> 4, m = nn & 15;
    int di = (((kb * 8 + nt) * 64) + quad * 16 + m) * 8 + e;
    hi[di] = h;
    lo[di] = l;
  } else if (b < 192 + pz) {
    int i = (b - 192) * 256 + t;
    if (i < GCOUNT * HDIM) pooled[i] = 0.f;
    else if (i - GCOUNT * HDIM < GCOUNT) gcnt[i - GCOUNT * HDIM] = 0.f;
    if (b == 192) {
      // sentinel row n: zero features in Sa and Sb, zero scales
      if (t < 16) S[(size_t)n * 16 + t] = make_uint2(0u, 0u);
      else if (t < 32) Sb[(size_t)n * 16 + (t - 16)] = make_uint2(0u, 0u);
      else if (t == 32) csaP[n] = 0.f;
      else if (t == 33) csbP[n] = 0.f;
    }
  } else if (b < 192 + pz + G) {
    int blk = b - 192 - pz;
    for (int i = t; i < NB1; i += 256) hist[i] = 0;
    __syncthreads();
    int base = blk * CHUNK;
    #pragma unroll
    for (int j = 0; j < CHUNK / 256; j++) {
      int e = base + j * 256 + t;
      if (e < E) atomicAdd(&hist[dst[e] >> 8], 1);
    }
    __syncthreads();
    for (int i = t; i < NB1; i += 256) gcount[i * G + blk] = hist[i];
  } else {
    int idx = (b - 192 - pz - G) * 16 + (t >> 4);
    int l = t & 15;
    int ridx = min(idx, n - 1);
    float4 f0 = ((const float4*)x)[(size_t)ridx * 32 + l * 2];
    float4 f1 = ((const float4*)x)[(size_t)ridx * 32 + l * 2 + 1];
    float v0 = f0.x, v1 = f0.y, v2 = f0.z, v3 = f0.w;
    float v4 = f1.x, v5 = f1.y, v6 = f1.z, v7 = f1.w;
    float mx = fmaxf(fmaxf(fmaxf(fabsf(v0), fabsf(v1)), fmaxf(fabsf(v2), fabsf(v3))),
                     fmaxf(fmaxf(fabsf(v4), fabsf(v5)), fmaxf(fabsf(v6), fabsf(v7))));
    mx = fmaxf(mx, __shfl_xor(mx, 1));
    mx = fmaxf(mx, __shfl_xor(mx, 2));
    mx = fmaxf(mx, __shfl_xor(mx, 4));
    mx = fmaxf(mx, __shfl_xor(mx, 8));
    float c = mx * (1.0f / 127.0f);
    float rinv = (mx > 0.f) ? 127.0f / mx : 0.f;
    if (idx < n) {
      unsigned lo = qb(v0, rinv) | (qb(v1, rinv) << 8) | (qb(v2, rinv) << 16) | (qb(v3, rinv) << 24);
      unsigned hi = qb(v4, rinv) | (qb(v5, rinv) << 8) | (qb(v6, rinv) << 16) | (qb(v7, rinv) << 24);
      S[(size_t)idx * 16 + l] = make_uint2(lo, hi);
      if (l == 0) cs_base[idx] = c;
    }
  }
}

// ------- scanA (1024 threads) / scanB -------

__global__ void scanA(int* __restrict__ g, int* __restrict__ bsum, int M) {
  __shared__ int sh[1024];
  int t = threadIdx.x;
  int i = blockIdx.x * 1024 + t;
  int v = (i < M) ? g[i] : 0;
  sh[t] = v;
  __syncthreads();
  for (int off = 1; off < 1024; off <<= 1) {
    int u = (t >= off) ? sh[t - off] : 0;
    __syncthreads();
    sh[t] += u;
    __syncthreads();
  }
  if (i < M) g[i] = sh[t] - v;
  if (t == 1023) bsum[blockIdx.x] = sh[1023];
}

__global__ void scanB(int* __restrict__ g, const int* __restrict__ bsum, int nb, int M) {
  __shared__ int sh[512];
  int t = threadIdx.x;
  if (t < 512) sh[t] = (t < nb) ? bsum[t] : 0;
  __syncthreads();
  for (int off = 1; off < 512; off <<= 1) {
    int u = (t < 512 && t >= off) ? sh[t - off] : 0;
    __syncthreads();
    if (t < 512) sh[t] += u;
    __syncthreads();
  }
  #pragma unroll
  for (int k = 0; k < 2; k++) {
    int i = blockIdx.x * 2048 + k * 1024 + t;
    if (i < M) {
      int j = i >> 10;
      if (j) g[i] += sh[j - 1];
    }
  }
}

// ------- rs_scatter: group (dst,src) by coarse bucket (dst>>8), LDS atomics only -------

__global__ void rs_scatter(const int* __restrict__ src, const int* __restrict__ dst,
                           const int* __restrict__ gscan, int E, int G, int NB1,
                           uint2* __restrict__ sp) {
  __shared__ int run[512];
  int blk = blockIdx.x, t = threadIdx.x;
  for (int i = t; i < NB1; i += 256) run[i] = gscan[i * G + blk];
  __syncthreads();
  int base = blk * CHUNK;
  #pragma unroll
  for (int j = 0; j < CHUNK / 256; j++) {
    int e = base + j * 256 + t;
    if (e < E) {
      int d = dst[e];
      int pos = atomicAdd(&run[d >> 8], 1);
      sp[pos] = make_uint2((unsigned)d, (unsigned)src[e]);
    }
  }
}

// ------- csr_fine (512 threads): PADDED rowp/rowe/col + dinv/cs per coarse bucket -------
// Rows padded to multiple of 4 edges with sentinel src = n (zero contribution).
// Padded bucket base PO = align4(O) + hb*1024 (max pad 3/row * 256 rows = 768 < 1024).

__global__ void csr_fine(const uint2* __restrict__ sp, const int* __restrict__ gscan,
                         int E, int G, int NB1,
                         int* __restrict__ rowp, int* __restrict__ rowe,
                         int* __restrict__ colv,
                         float* __restrict__ dinv, const float* __restrict__ cs_base,
                         float* __restrict__ cs, int n) {
  __shared__ int hist[256];
  __shared__ int scn[256];
  __shared__ int run2[256];
  int hb = blockIdx.x, t = threadIdx.x;
  int O = gscan[hb * G];
  int Oe = (hb == NB1 - 1) ? E : gscan[(hb + 1) * G];
  int PO = ((O + 3) & ~3) + hb * 1024;
  if (t < 256) hist[t] = 0;
  __syncthreads();
  for (int e = O + t; e < Oe; e += 512) atomicAdd(&hist[sp[e].x & 255], 1);
  __syncthreads();
  int v = 0, pv = 0;
  if (t < 256) { v = hist[t]; pv = (v + 3) & ~3; scn[t] = pv; }
  __syncthreads();
  for (int off = 1; off < 256; off <<= 1) {
    int u = (t < 256 && t >= off) ? scn[t - off] : 0;
    __syncthreads();
    if (t < 256) scn[t] += u;
    __syncthreads();
  }
  if (t < 256) {
    int st = PO + scn[t] - pv;
    run2[t] = st;
    int d = (hb << 8) + t;
    rowp[d] = st;
    rowe[d] = st + pv;
    for (int i = v; i < pv; i++) colv[st + i] = n;   // sentinel pads
    if (d < n) {
      float dv = rsqrtf((float)v + 1.0f);
      dinv[d] = dv;
      cs[d] = cs_base[d] * dv;
    }
  }
  __syncthreads();
  for (int e = O + t; e < Oe; e += 512) {
    uint2 p = sp[e];
    int pos = atomicAdd(&run2[p.x & 255], 1);
    colv[pos] = (int)p.y;
  }
}

// ------- int8 edge accumulate helper -------

__device__ __forceinline__ void acc8(uint2 v, float c, float* a) {
  int xx = (int)v.x, yy = (int)v.y;
  a[0] += c * (float)(signed char)(xx);
  a[1] += c * (float)(signed char)(xx >> 8);
  a[2] += c * (float)(signed char)(xx >> 16);
  a[3] += c * (float)(xx >> 24);
  a[4] += c * (float)(signed char)(yy);
  a[5] += c * (float)(signed char)(yy >> 8);
  a[6] += c * (float)(signed char)(yy >> 16);
  a[7] += c * (float)(yy >> 24);
}

// ===== fused agg + MFMA GEMM =====
// Block: 128 threads (2 waves), 32 rows. LDS: ONE 8KB region, time-shared:
//   phase 1: At (A bf16 fragments, XOR-swizzled, 32x16 uint4 = 8KB) -> av[] regs
//   phase 2: Wl (weights, one 8KB kb-plane at a time, 8 stages)
//   phase 3: epilogue staging
// Why 128 threads: grid 3125 blocks, static residency 16 blocks/CU (32 waves,
// 100%) vs round-7's 6.1 — occupancy was the limiting counter (42%) for the
// latency-bound gather. GEMM stays wave-local: wave w owns rows w*16..+15
// x all 128 cols, so the int8 row-max shfl reduction is unchanged.
// Agg inner loop identical to round 7 (4 rows/group, rotating 4-deep pipeline).

__device__ __forceinline__ void agg_phase(
    const uint2* __restrict__ S, const float* __restrict__ cs,
    const float* __restrict__ dinv,
    const int* __restrict__ rowp, const int* __restrict__ rowe,
    const int* __restrict__ col,
    uint4* At, int block0, int t, int n) {
  int grp = t >> 4, gl = t & 15;   // 8 groups x 16 lanes
  #pragma unroll 1
  for (int k = 0; k < 4; k++) {
    int lrow = grp * 4 + k;        // 0..31
    int g = block0 + lrow;
    uint4 o = make_uint4(0u, 0u, 0u, 0u);
    if (g < n) {
      float a[8];
      {
        uint2 q = S[(size_t)g * 16 + gl];
        float c = cs[g];
        int xx = (int)q.x, yy = (int)q.y;
        a[0] = c * (float)(signed char)(xx);
        a[1] = c * (float)(signed char)(xx >> 8);
        a[2] = c * (float)(signed char)(xx >> 16);
        a[3] = c * (float)(xx >> 24);
        a[4] = c * (float)(signed char)(yy);
        a[5] = c * (float)(signed char)(yy >> 8);
        a[6] = c * (float)(signed char)(yy >> 16);
        a[7] = c * (float)(yy >> 24);
      }
      int e = rowp[g], e1 = rowe[g];
      if (e < e1) {
        // prologue: issue quad 0's gathers
        int4 ca = *(const int4*)(col + e);
        uint2 q0 = S[(size_t)ca.x * 16 + gl];
        uint2 q1 = S[(size_t)ca.y * 16 + gl];
        uint2 q2 = S[(size_t)ca.z * 16 + gl];
        uint2 q3 = S[(size_t)ca.w * 16 + gl];
        float c0 = cs[ca.x], c1 = cs[ca.y], c2 = cs[ca.z], c3 = cs[ca.w];
        // steady state: issue quad i+1, consume quad i
        #pragma unroll 1
        for (e += 4; e < e1; e += 4) {
          int4 cn = *(const int4*)(col + e);
          uint2 p0 = S[(size_t)cn.x * 16 + gl];
          uint2 p1 = S[(size_t)cn.y * 16 + gl];
          uint2 p2 = S[(size_t)cn.z * 16 + gl];
          uint2 p3 = S[(size_t)cn.w * 16 + gl];
          float d0 = cs[cn.x], d1 = cs[cn.y], d2 = cs[cn.z], d3 = cs[cn.w];
          acc8(q0, c0, a); acc8(q1, c1, a); acc8(q2, c2, a); acc8(q3, c3, a);
          q0 = p0; q1 = p1; q2 = p2; q3 = p3;
          c0 = d0; c1 = d1; c2 = d2; c3 = d3;
        }
        // epilogue: consume the last quad
        acc8(q0, c0, a); acc8(q1, c1, a); acc8(q2, c2, a); acc8(q3, c3, a);
      }
      float d = dinv[g];
      o.x = pk2(a[0] * d, a[1] * d);
      o.y = pk2(a[2] * d, a[3] * d);
      o.z = pk2(a[4] * d, a[5] * d);
      o.w = pk2(a[6] * d, a[7] * d);
    }
    At[(gl << 5) + (lrow ^ (gl & 7))] = o;
  }
}

// stage one 8KB (512-uint4) weight kb-plane, identity copy (128 threads)
__device__ __forceinline__ void stage8(uint4* Wl, const uint4* __restrict__ WT, int t) {
  #pragma unroll
  for (int i = 0; i < 4; i++) {
    int idx = t + i * 128;
    Wl[idx] = WT[idx];
  }
}

// one kb-plane of MFMA (8 nt) against the staged chunk
__device__ __forceinline__ void mfma1(const uint4* Wl, uint4 avk, f32x4* acc, int lane) {
  short8 af = __builtin_bit_cast(short8, avk);
  #pragma unroll
  for (int nt = 0; nt < 8; nt++) {
    uint4 b = Wl[nt * 64 + lane];
    acc[nt] = __builtin_amdgcn_mfma_f32_16x16x32_bf16(af, __builtin_bit_cast(short8, b), acc[nt], 0, 0, 0);
  }
}

__global__ __launch_bounds__(128, 8) void fused_q8(
    const uint2* __restrict__ S, const float* __restrict__ cs,
    const float* __restrict__ dinv,
    const int* __restrict__ rowp, const int* __restrict__ rowe,
    const int* __restrict__ col,
    const uint4* __restrict__ WThi, const uint4* __restrict__ WTlo,
    const float* __restrict__ bias,
    unsigned char* __restrict__ Sout, float* __restrict__ csout, int n) {
  __shared__ __align__(16) char smem[8192];
  uint4* At = (uint4*)smem;
  uint4* Wl = (uint4*)smem;
  int t = threadIdx.x;
  int lane = t & 63, wv = t >> 6;
  int m = lane & 15, quad = lane >> 4;
  int block0 = blockIdx.x * 32;

  agg_phase(S, cs, dinv, rowp, rowe, col, At, block0, t, n);
  __syncthreads();

  uint4 av[4];
  #pragma unroll
  for (int kb = 0; kb < 4; kb++) {
    int glr = kb * 4 + quad;
    av[kb] = At[(glr << 5) + ((wv * 16 + m) ^ (glr & 7))];
  }
  __syncthreads();

  f32x4 acc[8];
  #pragma unroll
  for (int i = 0; i < 8; i++) acc[i] = (f32x4){0.f, 0.f, 0.f, 0.f};

  #pragma unroll
  for (int kb = 0; kb < 4; kb++) {
    stage8(Wl, WThi + kb * 512, t); __syncthreads();
    mfma1(Wl, av[kb], acc, lane);   __syncthreads();
  }
  #pragma unroll
  for (int kb = 0; kb < 4; kb++) {
    stage8(Wl, WTlo + kb * 512, t); __syncthreads();
    mfma1(Wl, av[kb], acc, lane);   __syncthreads();
  }

  // epilogue: relu + dinv prescale + int8 quant (staging reuses the region)
  char* stg = smem;
  float* LcA = (float*)(smem + 4608);
  #pragma unroll
  for (int r = 0; r < 4; r++) {
    int lrow = wv * 16 + quad * 4 + r;
    int grow = block0 + lrow;
    float sc = (grow < n) ? dinv[grow] : 0.f;
    float v[8];
    float mx = 0.f;
    #pragma unroll
    for (int nt = 0; nt < 8; nt++) {
      v[nt] = fmaxf(acc[nt][r] + bias[nt * 16 + m], 0.f) * sc;
      mx = fmaxf(mx, v[nt]);
    }
    mx = fmaxf(mx, __shfl_xor(mx, 1));
    mx = fmaxf(mx, __shfl_xor(mx, 2));
    mx = fmaxf(mx, __shfl_xor(mx, 4));
    mx = fmaxf(mx, __shfl_xor(mx, 8));
    float c = mx * (1.0f / 127.0f);
    float rinv = (mx > 0.f) ? 127.0f / mx : 0.f;
    #pragma unroll
    for (int nt = 0; nt < 8; nt++) {
      stg[lrow * 144 + nt * 16 + m] = (char)(int)rintf(v[nt] * rinv);
    }
    if (m == 0) LcA[lrow] = c;
  }
  __syncthreads();
  #pragma unroll
  for (int z = 0; z < 2; z++) {
    int i = t + z * 128;
    int lrow = i >> 3, seg = i & 7;
    int grow = block0 + lrow;
    if (grow < n)
      ((uint4*)Sout)[(size_t)grow * 8 + seg] = *(const uint4*)&stg[lrow * 144 + seg * 16];
  }
  if (t < 32 && block0 + t < n) csout[block0 + t] = LcA[t];
}

__global__ __launch_bounds__(128, 8) void fused_final(
    const uint2* __restrict__ S, const float* __restrict__ cs,
    const float* __restrict__ dinv,
    const int* __restrict__ rowp, const int* __restrict__ rowe,
    const int* __restrict__ col,
    const uint4* __restrict__ WThi, const uint4* __restrict__ WTlo,
    const float* __restrict__ bias, const int* __restrict__ batch,
    float* __restrict__ pooled, float* __restrict__ gcnt, int n) {
  __shared__ __align__(16) char smem[8192];
  uint4* At = (uint4*)smem;
  uint4* Wl = (uint4*)smem;
  int t = threadIdx.x;
  int lane = t & 63, wv = t >> 6;
  int m = lane & 15, quad = lane >> 4;
  int block0 = blockIdx.x * 32;

  agg_phase(S, cs, dinv, rowp, rowe, col, At, block0, t, n);
  __syncthreads();

  uint4 av[4];
  #pragma unroll
  for (int kb = 0; kb < 4; kb++) {
    int glr = kb * 4 + quad;
    av[kb] = At[(glr << 5) + ((wv * 16 + m) ^ (glr & 7))];
  }
  __syncthreads();

  f32x4 acc[8];
  #pragma unroll
  for (int i = 0; i < 8; i++) acc[i] = (f32x4){0.f, 0.f, 0.f, 0.f};

  #pragma unroll
  for (int kb = 0; kb < 4; kb++) {
    stage8(Wl, WThi + kb * 512, t); __syncthreads();
    mfma1(Wl, av[kb], acc, lane);   __syncthreads();
  }
  #pragma unroll
  for (int kb = 0; kb < 4; kb++) {
    stage8(Wl, WTlo + kb * 512, t); __syncthreads();
    mfma1(Wl, av[kb], acc, lane);   __syncthreads();
  }

  // epilogue: relu -> bf16 staging (32x128 ushort = 8KB), then pool partials
  unsigned short* Ls = (unsigned short*)smem;
  #pragma unroll
  for (int r = 0; r < 4; r++) {
    int lrow = wv * 16 + quad * 4 + r;
    #pragma unroll
    for (int nt = 0; nt < 8; nt++) {
      float v = fmaxf(acc[nt][r] + bias[nt * 16 + m], 0.f);
      Ls[lrow * 128 + nt * 16 + m] = f2bf(v);
    }
  }
  __syncthreads();
  {
    float a2 = 0.f, cl = 0.f;
    int gcur = -1;
    for (int r = 0; r < 32; r++) {
      int grow = block0 + r;
      if (grow >= n) break;
      int gr = batch[grow];
      if (gr != gcur) {
        if (gcur >= 0) {
          atomicAdd(&pooled[gcur * HDIM + t], a2);
          if (t == 0) atomicAdd(&gcnt[gcur], cl);
        }
        a2 = 0.f; cl = 0.f; gcur = gr;
      }
      a2 += bfl((unsigned)Ls[r * 128 + t]);
      cl += 1.f;
    }
    if (gcur >= 0) {
      atomicAdd(&pooled[gcur * HDIM + t], a2);
      if (t == 0) atomicAdd(&gcnt[gcur], cl);
    }
  }
}

// ------- classifier head -------

__global__ void cls_kernel(const float* __restrict__ pooled, const float* __restrict__ gcnt,
                           const float* __restrict__ Wc1, const float* __restrict__ bc1,
                           const float* __restrict__ Wc2, const float* __restrict__ bc2,
                           float* __restrict__ out) {
  __shared__ float p[HDIM];
  __shared__ float r0s[HDIM], r1s[HDIM];
  int g = blockIdx.x, t = threadIdx.x;
  float c = fmaxf(gcnt[g], 1.0f);
  p[t] = pooled[g * HDIM + t] / c;
  __syncthreads();
  float acc = bc1[t];
  for (int k = 0; k < HDIM; k++) {
    acc += p[k] * (Wc1[k * HDIM + t] + Wc1[(HDIM + k) * HDIM + t]);
  }
  float h = fmaxf(acc, 0.f);
  r0s[t] = h * Wc2[t * 2 + 0];
  r1s[t] = h * Wc2[t * 2 + 1];
  __syncthreads();
  for (int s2 = 64; s2 > 0; s2 >>= 1) {
    if (t < s2) { r0s[t] += r0s[t + s2]; r1s[t] += r1s[t + s2]; }
    __syncthreads();
  }
  if (t == 0) {
    out[g * 2 + 0] = r0s[0] + bc2[0];
    out[g * 2 + 1] = r1s[0] + bc2[1];
  }
}

// ------- launch -------

extern "C" void kernel_launch(void* const* d_in, const int* in_sizes, int n_in,
                              void* d_out, int out_size, void* d_ws, size_t ws_size,
                              hipStream_t stream) {
  const float* x   = (const float*)d_in[0];
  const int*   ei  = (const int*)d_in[1];
  const int*   bat = (const int*)d_in[2];
  const float* W0  = (const float*)d_in[3];
  const float* b0  = (const float*)d_in[4];
  const float* W1  = (const float*)d_in[5];
  const float* b1  = (const float*)d_in[6];
  const float* W2  = (const float*)d_in[7];
  const float* b2  = (const float*)d_in[8];
  const float* Wc1 = (const float*)d_in[9];
  const float* bc1 = (const float*)d_in[10];
  const float* Wc2 = (const float*)d_in[11];
  const float* bc2 = (const float*)d_in[12];
  float* out = (float*)d_out;

  int N = in_sizes[0] / HDIM;
  int E = in_sizes[1] / 2;
  const int* src = ei;
  const int* dst = ei + E;

  int NB1 = (N + 255) >> 8;
  int G = (E + CHUNK - 1) / CHUNK;
  int M = NB1 * G;

  char* ws = (char*)d_ws;
  size_t off = 0;
  auto alloc = [&](size_t bytes) -> void* {
    void* p = (void*)(ws + off);
    off += (bytes + 511) & ~(size_t)511;
    return p;
  };
  // N+1 rows per state buffer (row N = sentinel, zeroed once in mega1)
  unsigned char* Sa = (unsigned char*)alloc((size_t)(N + 1) * HDIM * 2);
  unsigned char* Sb = Sa + (size_t)(N + 1) * HDIM;
  float* csa  = (float*)alloc((size_t)(N + 2) * 4);
  float* csb  = (float*)alloc((size_t)(N + 2) * 4);
  float* cs_base = (float*)alloc((size_t)N * 4);
  float* dinv = (float*)alloc((size_t)N * 4);
  int*   rowp = (int*)alloc((size_t)(NB1 * 256 + 2) * 4);
  int*   rowe = (int*)alloc((size_t)(NB1 * 256 + 2) * 4);
  int*   colv = (int*)alloc((size_t)(E + NB1 * 1024 + 1024) * 4);
  uint2* sp   = (uint2*)alloc((size_t)E * 8);
  float* pooled = (float*)alloc((size_t)GCOUNT * HDIM * 4);
  float* gcnt   = (float*)alloc((size_t)GCOUNT * 4);
  unsigned short* wt_hi[3], *wt_lo[3];
  for (int i = 0; i < 3; i++) {
    wt_hi[i] = (unsigned short*)alloc(HDIM * HDIM * 2);
    wt_lo[i] = (unsigned short*)alloc(HDIM * HDIM * 2);
  }
  int* gcount = (int*)alloc((size_t)(M + 2) * 4);
  int nbM = (M + 1023) / 1024;
  int* bsum = (int*)alloc((size_t)nbM * 4);

  // 1. mega1
  int pz = (GCOUNT * HDIM + GCOUNT + 255) / 256;
  int psb = (N + 15) / 16;
  mega1<<<192 + pz + G + psb, 256, 0, stream>>>(W0, W1, W2,
      wt_hi[0], wt_lo[0], wt_hi[1], wt_lo[1], wt_hi[2], wt_lo[2],
      pooled, gcnt, pz, dst, E, G, NB1, gcount,
      x, (uint2*)Sa, (uint2*)Sb, csa, csb, cs_base, N);

  // 2-3. scans
  scanA<<<nbM, 1024, 0, stream>>>(gcount, bsum, M);
  scanB<<<(M + 2047) / 2048, 1024, 0, stream>>>(gcount, bsum, nbM, M);

  // 4-5. scatter + fine CSR (padded)
  rs_scatter<<<G, 256, 0, stream>>>(src, dst, gcount, E, G, NB1, sp);
  csr_fine<<<NB1, 512, 0, stream>>>(sp, gcount, E, G, NB1, rowp, rowe, colv,
      dinv, cs_base, csa, N);

  // 6-8. fused agg+gemm per layer, pool folded into layer 2
  int fusedBlocks = (N + 31) / 32;

  fused_q8<<<fusedBlocks, 128, 0, stream>>>((const uint2*)Sa, csa, dinv, rowp, rowe, colv,
      (const uint4*)wt_hi[0], (const uint4*)wt_lo[0], b0, Sb, csb, N);

  fused_q8<<<fusedBlocks, 128, 0, stream>>>((const uint2*)Sb, csb, dinv, rowp, rowe, colv,
      (const uint4*)wt_hi[1], (const uint4*)wt_lo[1], b1, Sa, csa, N);

  fused_final<<<fusedBlocks, 128, 0, stream>>>((const uint2*)Sa, csa, dinv, rowp, rowe, colv,
      (const uint4*)wt_hi[2], (const uint4*)wt_lo[2], b2, bat, pooled, gcnt, N);

  // 9. classifier
  cls_kernel<<<GCOUNT, HDIM, 0, stream>>>(pooled, gcnt, Wc1, bc1, Wc2, bc2, out);
}

// Round 10
// 315.370 us; speedup vs baseline: 1.1301x; 1.1301x over previous
//
#include <hip/hip_runtime.h>

#define HDIM 128
#define GCOUNT 64
#define CHUNK 2048

// ---- bf16 helpers (manual, RNE) ----
__device__ __forceinline__ float bfl(unsigned u) { return __uint_as_float(u << 16); }
__device__ __forceinline__ unsigned short f2bf(float f) {
  unsigned u = __float_as_uint(f);
  unsigned r = (u + 0x7fffu + ((u >> 16) & 1u)) >> 16;
  return (unsigned short)r;
}
__device__ __forceinline__ unsigned pk2(float a, float b) {
  return (unsigned)f2bf(a) | ((unsigned)f2bf(b) << 16);
}

typedef __attribute__((ext_vector_type(8))) short short8;
typedef __attribute__((ext_vector_type(4))) float f32x4;

__device__ __forceinline__ unsigned qb(float v, float rinv) {
  int q = (int)rintf(v * rinv);
  return (unsigned)(q & 0xff);
}

// ------- mega1: weight transpose->fragment order | zero pooled/gcnt/sentinels |
//         coarse hist | prescale int8 -------
// Weight fragment layout (ushort index):
//   di = ((kb*8 + nt)*64 + quad*16 + m)*8 + e
// k = kb*32 + quad*8 + e (input feature), nn = nt*16 + m (output feature).
// GEMM-side LDS stage is an identity copy, chunkable in 1024-uint4 (16KB) halves.

__global__ void mega1(const float* __restrict__ W0, const float* __restrict__ W1,
                      const float* __restrict__ W2,
                      unsigned short* __restrict__ h0, unsigned short* __restrict__ l0,
                      unsigned short* __restrict__ h1, unsigned short* __restrict__ l1,
                      unsigned short* __restrict__ h2, unsigned short* __restrict__ l2,
                      float* __restrict__ pooled, float* __restrict__ gcnt, int pz,
                      const int* __restrict__ dst, int E, int G, int NB1,
                      int* __restrict__ gcount,
                      const float* __restrict__ x, uint2* __restrict__ S,
                      uint2* __restrict__ Sb, float* __restrict__ csaP,
                      float* __restrict__ csbP,
                      float* __restrict__ cs_base, int n) {
  __shared__ int hist[512];
  int b = blockIdx.x, t = threadIdx.x;
  if (b < 192) {
    int w = b >> 6;
    int idx = (b & 63) * 256 + t;
    const float* W = (w == 0) ? W0 : (w == 1) ? W1 : W2;
    unsigned short* hi = (w == 0) ? h0 : (w == 1) ? h1 : h2;
    unsigned short* lo = (w == 0) ? l0 : (w == 1) ? l1 : l2;
    int k = idx >> 7, nn = idx & 127;
    float wv = W[idx];
    unsigned short h = f2bf(wv);
    float hf = __uint_as_float((unsigned)h << 16);
    unsigned short l = f2bf(wv - hf);
    int kb = k >> 5, quad = (k >> 3) & 3, e = k & 7;
    int nt = nn >> 4, m = nn & 15;
    int di = (((kb * 8 + nt) * 64) + quad * 16 + m) * 8 + e;
    hi[di] = h;
    lo[di] = l;
  } else if (b < 192 + pz) {
    int i = (b - 192) * 256 + t;
    if (i < GCOUNT * HDIM) pooled[i] = 0.f;
    else if (i - GCOUNT * HDIM < GCOUNT) gcnt[i - GCOUNT * HDIM] = 0.f;
    if (b == 192) {
      // sentinel row n: zero features in Sa and Sb, zero scales
      if (t < 16) S[(size_t)n * 16 + t] = make_uint2(0u, 0u);
      else if (t < 32) Sb[(size_t)n * 16 + (t - 16)] = make_uint2(0u, 0u);
      else if (t == 32) csaP[n] = 0.f;
      else if (t == 33) csbP[n] = 0.f;
    }
  } else if (b < 192 + pz + G) {
    int blk = b - 192 - pz;
    for (int i = t; i < NB1; i += 256) hist[i] = 0;
    __syncthreads();
    int base = blk * CHUNK;
    #pragma unroll
    for (int j = 0; j < CHUNK / 256; j++) {
      int e = base + j * 256 + t;
      if (e < E) atomicAdd(&hist[dst[e] >> 8], 1);
    }
    __syncthreads();
    for (int i = t; i < NB1; i += 256) gcount[i * G + blk] = hist[i];
  } else {
    int idx = (b - 192 - pz - G) * 16 + (t >> 4);
    int l = t & 15;
    int ridx = min(idx, n - 1);
    float4 f0 = ((const float4*)x)[(size_t)ridx * 32 + l * 2];
    float4 f1 = ((const float4*)x)[(size_t)ridx * 32 + l * 2 + 1];
    float v0 = f0.x, v1 = f0.y, v2 = f0.z, v3 = f0.w;
    float v4 = f1.x, v5 = f1.y, v6 = f1.z, v7 = f1.w;
    float mx = fmaxf(fmaxf(fmaxf(fabsf(v0), fabsf(v1)), fmaxf(fabsf(v2), fabsf(v3))),
                     fmaxf(fmaxf(fabsf(v4), fabsf(v5)), fmaxf(fabsf(v6), fabsf(v7))));
    mx = fmaxf(mx, __shfl_xor(mx, 1));
    mx = fmaxf(mx, __shfl_xor(mx, 2));
    mx = fmaxf(mx, __shfl_xor(mx, 4));
    mx = fmaxf(mx, __shfl_xor(mx, 8));
    float c = mx * (1.0f / 127.0f);
    float rinv = (mx > 0.f) ? 127.0f / mx : 0.f;
    if (idx < n) {
      unsigned lo = qb(v0, rinv) | (qb(v1, rinv) << 8) | (qb(v2, rinv) << 16) | (qb(v3, rinv) << 24);
      unsigned hi = qb(v4, rinv) | (qb(v5, rinv) << 8) | (qb(v6, rinv) << 16) | (qb(v7, rinv) << 24);
      S[(size_t)idx * 16 + l] = make_uint2(lo, hi);
      if (l == 0) cs_base[idx] = c;
    }
  }
}

// ------- scanA (1024 threads): per-block exclusive scan + block sums -------
// (scanB is eliminated: consumers apply the bsum correction inline.)

__global__ void scanA(int* __restrict__ g, int* __restrict__ bsum, int M) {
  __shared__ int sh[1024];
  int t = threadIdx.x;
  int i = blockIdx.x * 1024 + t;
  int v = (i < M) ? g[i] : 0;
  sh[t] = v;
  __syncthreads();
  for (int off = 1; off < 1024; off <<= 1) {
    int u = (t >= off) ? sh[t - off] : 0;
    __syncthreads();
    sh[t] += u;
    __syncthreads();
  }
  if (i < M) g[i] = sh[t] - v;
  if (t == 1023) bsum[blockIdx.x] = sh[1023];
}

// ------- rs_scatter (512 threads): group by coarse bucket (dst>>8) -------
// Applies the bsum correction inline (inclusive LDS scan of bsum, nb <= 512).
// PACKED u32 entries: src | (dst&255)<<24  (src < 2^24).

__global__ void rs_scatter(const int* __restrict__ src, const int* __restrict__ dst,
                           const int* __restrict__ gscan, const int* __restrict__ bsum,
                           int nb, int E, int G, int NB1,
                           unsigned* __restrict__ sp) {
  __shared__ int run[512];
  __shared__ int sb[512];
  int blk = blockIdx.x, t = threadIdx.x;
  sb[t] = (t < nb) ? bsum[t] : 0;
  __syncthreads();
  for (int off = 1; off < 512; off <<= 1) {
    int u = (t >= off) ? sb[t - off] : 0;
    __syncthreads();
    sb[t] += u;
    __syncthreads();
  }
  for (int i = t; i < NB1; i += 512) {
    int idx = i * G + blk;
    int j = idx >> 10;
    run[i] = gscan[idx] + (j ? sb[j - 1] : 0);
  }
  __syncthreads();
  int base = blk * CHUNK;
  #pragma unroll
  for (int j = 0; j < CHUNK / 512; j++) {
    int e = base + j * 512 + t;
    if (e < E) {
      int d = dst[e];
      int pos = atomicAdd(&run[d >> 8], 1);
      sp[pos] = (unsigned)src[e] | ((unsigned)(d & 255) << 24);
    }
  }
}

// ------- csr_fine (512 threads): PADDED rowpe/col + dinv/cs per coarse bucket -------
// Rows padded to multiple of 4 edges with sentinel src = n (zero contribution).
// Padded bucket base PO = align4(O) + hb*1024 (max pad 3/row * 256 rows = 768 < 1024).
// Applies bsum correction inline for O / Oe.

__global__ void csr_fine(const unsigned* __restrict__ sp, const int* __restrict__ gscan,
                         const int* __restrict__ bsum, int nb,
                         int E, int G, int NB1,
                         int2* __restrict__ rowpe, int* __restrict__ colv,
                         float* __restrict__ dinv, const float* __restrict__ cs_base,
                         float* __restrict__ cs, int n) {
  __shared__ int sb[512];
  __shared__ int hist[256];
  __shared__ int scn[256];
  __shared__ int run2[256];
  int hb = blockIdx.x, t = threadIdx.x;
  sb[t] = (t < nb) ? bsum[t] : 0;
  __syncthreads();
  for (int off = 1; off < 512; off <<= 1) {
    int u = (t >= off) ? sb[t - off] : 0;
    __syncthreads();
    sb[t] += u;
    __syncthreads();
  }
  int iO = hb * G;
  int jO = iO >> 10;
  int O = gscan[iO] + (jO ? sb[jO - 1] : 0);
  int Oe;
  if (hb == NB1 - 1) Oe = E;
  else {
    int i2 = (hb + 1) * G;
    int j2 = i2 >> 10;
    Oe = gscan[i2] + (j2 ? sb[j2 - 1] : 0);
  }
  int PO = ((O + 3) & ~3) + hb * 1024;
  if (t < 256) hist[t] = 0;
  __syncthreads();
  for (int e = O + t; e < Oe; e += 512) atomicAdd(&hist[sp[e] >> 24], 1);
  __syncthreads();
  int v = 0, pv = 0;
  if (t < 256) { v = hist[t]; pv = (v + 3) & ~3; scn[t] = pv; }
  __syncthreads();
  for (int off = 1; off < 256; off <<= 1) {
    int u = (t < 256 && t >= off) ? scn[t - off] : 0;
    __syncthreads();
    if (t < 256) scn[t] += u;
    __syncthreads();
  }
  if (t < 256) {
    int st = PO + scn[t] - pv;
    run2[t] = st;
    int d = (hb << 8) + t;
    rowpe[d] = make_int2(st, st + pv);
    for (int i = v; i < pv; i++) colv[st + i] = n;   // sentinel pads
    if (d < n) {
      float dv = rsqrtf((float)v + 1.0f);
      dinv[d] = dv;
      cs[d] = cs_base[d] * dv;
    }
  }
  __syncthreads();
  for (int e = O + t; e < Oe; e += 512) {
    unsigned p = sp[e];
    int pos = atomicAdd(&run2[p >> 24], 1);
    colv[pos] = (int)(p & 0xFFFFFFu);
  }
}

// ------- int8 edge accumulate helper -------

__device__ __forceinline__ void acc8(uint2 v, float c, float* a) {
  int xx = (int)v.x, yy = (int)v.y;
  a[0] += c * (float)(signed char)(xx);
  a[1] += c * (float)(signed char)(xx >> 8);
  a[2] += c * (float)(signed char)(xx >> 16);
  a[3] += c * (float)(xx >> 24);
  a[4] += c * (float)(signed char)(yy);
  a[5] += c * (float)(signed char)(yy >> 8);
  a[6] += c * (float)(signed char)(yy >> 16);
  a[7] += c * (float)(yy >> 24);
}

// ===== fused agg + MFMA GEMM (round-7 structure, unchanged) =====
// Block: 256 threads (4 waves), 64 rows. LDS: ONE 16KB region, time-shared.
// Gather: 1-iteration-deep rotating pipeline — iteration i issues quad i+1's
// col load + 4 S-gathers + 4 scale loads, then consumes quad i's registers.

__device__ __forceinline__ void agg_phase(
    const uint2* __restrict__ S, const float* __restrict__ cs,
    const float* __restrict__ dinv,
    const int2* __restrict__ rowpe,
    const int* __restrict__ col,
    uint4* At, int block0, int t, int n) {
  int grp = t >> 4, gl = t & 15;
  #pragma unroll 1
  for (int k = 0; k < 4; k++) {
    int lrow = grp * 4 + k;
    int g = block0 + lrow;
    uint4 o = make_uint4(0u, 0u, 0u, 0u);
    if (g < n) {
      float a[8];
      {
        uint2 q = S[(size_t)g * 16 + gl];
        float c = cs[g];
        int xx = (int)q.x, yy = (int)q.y;
        a[0] = c * (float)(signed char)(xx);
        a[1] = c * (float)(signed char)(xx >> 8);
        a[2] = c * (float)(signed char)(xx >> 16);
        a[3] = c * (float)(xx >> 24);
        a[4] = c * (float)(signed char)(yy);
        a[5] = c * (float)(signed char)(yy >> 8);
        a[6] = c * (float)(signed char)(yy >> 16);
        a[7] = c * (float)(yy >> 24);
      }
      int2 pe = rowpe[g];
      int e = pe.x, e1 = pe.y;
      if (e < e1) {
        // prologue: issue quad 0's gathers
        int4 ca = *(const int4*)(col + e);
        uint2 q0 = S[(size_t)ca.x * 16 + gl];
        uint2 q1 = S[(size_t)ca.y * 16 + gl];
        uint2 q2 = S[(size_t)ca.z * 16 + gl];
        uint2 q3 = S[(size_t)ca.w * 16 + gl];
        float c0 = cs[ca.x], c1 = cs[ca.y], c2 = cs[ca.z], c3 = cs[ca.w];
        // steady state: issue quad i+1, consume quad i
        #pragma unroll 1
        for (e += 4; e < e1; e += 4) {
          int4 cn = *(const int4*)(col + e);
          uint2 p0 = S[(size_t)cn.x * 16 + gl];
          uint2 p1 = S[(size_t)cn.y * 16 + gl];
          uint2 p2 = S[(size_t)cn.z * 16 + gl];
          uint2 p3 = S[(size_t)cn.w * 16 + gl];
          float d0 = cs[cn.x], d1 = cs[cn.y], d2 = cs[cn.z], d3 = cs[cn.w];
          acc8(q0, c0, a); acc8(q1, c1, a); acc8(q2, c2, a); acc8(q3, c3, a);
          q0 = p0; q1 = p1; q2 = p2; q3 = p3;
          c0 = d0; c1 = d1; c2 = d2; c3 = d3;
        }
        // epilogue: consume the last quad
        acc8(q0, c0, a); acc8(q1, c1, a); acc8(q2, c2, a); acc8(q3, c3, a);
      }
      float d = dinv[g];
      o.x = pk2(a[0] * d, a[1] * d);
      o.y = pk2(a[2] * d, a[3] * d);
      o.z = pk2(a[4] * d, a[5] * d);
      o.w = pk2(a[6] * d, a[7] * d);
    }
    At[(gl << 6) + (lrow ^ (gl & 7))] = o;
  }
}

// stage one 16KB (1024-uint4) weight chunk, identity copy
__device__ __forceinline__ void stage16(uint4* Wl, const uint4* __restrict__ WT, int t) {
  #pragma unroll
  for (int i = 0; i < 4; i++) {
    int idx = t + i * 256;
    Wl[idx] = WT[idx];
  }
}

// run 2 kb-planes of MFMA against the currently staged chunk (kbase = 0 or 2)
__device__ __forceinline__ void mfma2(const uint4* Wl, const uint4* av, f32x4* acc,
                                      int kbase, int lane) {
  #pragma unroll
  for (int kk = 0; kk < 2; kk++) {
    short8 af = __builtin_bit_cast(short8, av[kbase + kk]);
    #pragma unroll
    for (int nt = 0; nt < 8; nt++) {
      uint4 b = Wl[(kk * 8 + nt) * 64 + lane];
      acc[nt] = __builtin_amdgcn_mfma_f32_16x16x32_bf16(af, __builtin_bit_cast(short8, b), acc[nt], 0, 0, 0);
    }
  }
}

__global__ __launch_bounds__(256, 4) void fused_q8(
    const uint2* __restrict__ S, const float* __restrict__ cs,
    const float* __restrict__ dinv,
    const int2* __restrict__ rowpe,
    const int* __restrict__ col,
    const uint4* __restrict__ WThi, const uint4* __restrict__ WTlo,
    const float* __restrict__ bias,
    unsigned char* __restrict__ Sout, float* __restrict__ csout, int n) {
  __shared__ __align__(16) char smem[16384];
  uint4* At = (uint4*)smem;
  uint4* Wl = (uint4*)smem;
  int t = threadIdx.x;
  int lane = t & 63, wv = t >> 6;
  int m = lane & 15, quad = lane >> 4;
  int block0 = blockIdx.x * 64;

  agg_phase(S, cs, dinv, rowpe, col, At, block0, t, n);
  __syncthreads();

  uint4 av[4];
  #pragma unroll
  for (int kb = 0; kb < 4; kb++) {
    int glr = kb * 4 + quad;
    av[kb] = At[(glr << 6) + ((wv * 16 + m) ^ (glr & 7))];
  }
  __syncthreads();

  f32x4 acc[8];
  #pragma unroll
  for (int i = 0; i < 8; i++) acc[i] = (f32x4){0.f, 0.f, 0.f, 0.f};

  stage16(Wl, WThi, t);        __syncthreads();
  mfma2(Wl, av, acc, 0, lane); __syncthreads();
  stage16(Wl, WThi + 1024, t); __syncthreads();
  mfma2(Wl, av, acc, 2, lane); __syncthreads();
  stage16(Wl, WTlo, t);        __syncthreads();
  mfma2(Wl, av, acc, 0, lane); __syncthreads();
  stage16(Wl, WTlo + 1024, t); __syncthreads();
  mfma2(Wl, av, acc, 2, lane); __syncthreads();

  // epilogue: relu + dinv prescale + int8 quant (staging reuses the region)
  char* stg = smem;
  float* LcA = (float*)(smem + 9216);
  #pragma unroll
  for (int r = 0; r < 4; r++) {
    int lrow = wv * 16 + quad * 4 + r;
    int grow = block0 + lrow;
    float sc = (grow < n) ? dinv[grow] : 0.f;
    float v[8];
    float mx = 0.f;
    #pragma unroll
    for (int nt = 0; nt < 8; nt++) {
      v[nt] = fmaxf(acc[nt][r] + bias[nt * 16 + m], 0.f) * sc;
      mx = fmaxf(mx, v[nt]);
    }
    mx = fmaxf(mx, __shfl_xor(mx, 1));
    mx = fmaxf(mx, __shfl_xor(mx, 2));
    mx = fmaxf(mx, __shfl_xor(mx, 4));
    mx = fmaxf(mx, __shfl_xor(mx, 8));
    float c = mx * (1.0f / 127.0f);
    float rinv = (mx > 0.f) ? 127.0f / mx : 0.f;
    #pragma unroll
    for (int nt = 0; nt < 8; nt++) {
      stg[lrow * 144 + nt * 16 + m] = (char)(int)rintf(v[nt] * rinv);
    }
    if (m == 0) LcA[lrow] = c;
  }
  __syncthreads();
  for (int i = t; i < 512; i += 256) {
    int lrow = i >> 3, seg = i & 7;
    int grow = block0 + lrow;
    if (grow < n)
      ((uint4*)Sout)[(size_t)grow * 8 + seg] = *(const uint4*)&stg[lrow * 144 + seg * 16];
  }
  if (t < 64 && block0 + t < n) csout[block0 + t] = LcA[t];
}

__global__ __launch_bounds__(256, 4) void fused_final(
    const uint2* __restrict__ S, const float* __restrict__ cs,
    const float* __restrict__ dinv,
    const int2* __restrict__ rowpe,
    const int* __restrict__ col,
    const uint4* __restrict__ WThi, const uint4* __restrict__ WTlo,
    const float* __restrict__ bias, const int* __restrict__ batch,
    float* __restrict__ pooled, float* __restrict__ gcnt, int n) {
  __shared__ __align__(16) char smem[16384];
  uint4* At = (uint4*)smem;
  uint4* Wl = (uint4*)smem;
  int t = threadIdx.x;
  int lane = t & 63, wv = t >> 6;
  int m = lane & 15, quad = lane >> 4;
  int block0 = blockIdx.x * 64;

  agg_phase(S, cs, dinv, rowpe, col, At, block0, t, n);
  __syncthreads();

  uint4 av[4];
  #pragma unroll
  for (int kb = 0; kb < 4; kb++) {
    int glr = kb * 4 + quad;
    av[kb] = At[(glr << 6) + ((wv * 16 + m) ^ (glr & 7))];
  }
  __syncthreads();

  f32x4 acc[8];
  #pragma unroll
  for (int i = 0; i < 8; i++) acc[i] = (f32x4){0.f, 0.f, 0.f, 0.f};

  stage16(Wl, WThi, t);        __syncthreads();
  mfma2(Wl, av, acc, 0, lane); __syncthreads();
  stage16(Wl, WThi + 1024, t); __syncthreads();
  mfma2(Wl, av, acc, 2, lane); __syncthreads();
  stage16(Wl, WTlo, t);        __syncthreads();
  mfma2(Wl, av, acc, 0, lane); __syncthreads();
  stage16(Wl, WTlo + 1024, t); __syncthreads();
  mfma2(Wl, av, acc, 2, lane); __syncthreads();

  // epilogue: relu -> bf16 staging (64x128 ushort = 16KB), then pool partials
  unsigned short* Ls = (unsigned short*)smem;
  #pragma unroll
  for (int r = 0; r < 4; r++) {
    int lrow = wv * 16 + quad * 4 + r;
    #pragma unroll
    for (int nt = 0; nt < 8; nt++) {
      float v = fmaxf(acc[nt][r] + bias[nt * 16 + m], 0.f);
      Ls[lrow * 128 + nt * 16 + m] = f2bf(v);
    }
  }
  __syncthreads();
  if (t < 128) {
    float a2 = 0.f, cl = 0.f;
    int gcur = -1;
    for (int r = 0; r < 64; r++) {
      int grow = block0 + r;
      if (grow >= n) break;
      int gr = batch[grow];
      if (gr != gcur) {
        if (gcur >= 0) {
          atomicAdd(&pooled[gcur * HDIM + t], a2);
          if (t == 0) atomicAdd(&gcnt[gcur], cl);
        }
        a2 = 0.f; cl = 0.f; gcur = gr;
      }
      a2 += bfl((unsigned)Ls[r * 128 + t]);
      cl += 1.f;
    }
    if (gcur >= 0) {
      atomicAdd(&pooled[gcur * HDIM + t], a2);
      if (t == 0) atomicAdd(&gcnt[gcur], cl);
    }
  }
}

// ------- classifier head -------

__global__ void cls_kernel(const float* __restrict__ pooled, const float* __restrict__ gcnt,
                           const float* __restrict__ Wc1, const float* __restrict__ bc1,
                           const float* __restrict__ Wc2, const float* __restrict__ bc2,
                           float* __restrict__ out) {
  __shared__ float p[HDIM];
  __shared__ float r0s[HDIM], r1s[HDIM];
  int g = blockIdx.x, t = threadIdx.x;
  float c = fmaxf(gcnt[g], 1.0f);
  p[t] = pooled[g * HDIM + t] / c;
  __syncthreads();
  float acc = bc1[t];
  for (int k = 0; k < HDIM; k++) {
    acc += p[k] * (Wc1[k * HDIM + t] + Wc1[(HDIM + k) * HDIM + t]);
  }
  float h = fmaxf(acc, 0.f);
  r0s[t] = h * Wc2[t * 2 + 0];
  r1s[t] = h * Wc2[t * 2 + 1];
  __syncthreads();
  for (int s2 = 64; s2 > 0; s2 >>= 1) {
    if (t < s2) { r0s[t] += r0s[t + s2]; r1s[t] += r1s[t + s2]; }
    __syncthreads();
  }
  if (t == 0) {
    out[g * 2 + 0] = r0s[0] + bc2[0];
    out[g * 2 + 1] = r1s[0] + bc2[1];
  }
}

// ------- launch -------

extern "C" void kernel_launch(void* const* d_in, const int* in_sizes, int n_in,
                              void* d_out, int out_size, void* d_ws, size_t ws_size,
                              hipStream_t stream) {
  const float* x   = (const float*)d_in[0];
  const int*   ei  = (const int*)d_in[1];
  const int*   bat = (const int*)d_in[2];
  const float* W0  = (const float*)d_in[3];
  const float* b0  = (const float*)d_in[4];
  const float* W1  = (const float*)d_in[5];
  const float* b1  = (const float*)d_in[6];
  const float* W2  = (const float*)d_in[7];
  const float* b2  = (const float*)d_in[8];
  const float* Wc1 = (const float*)d_in[9];
  const float* bc1 = (const float*)d_in[10];
  const float* Wc2 = (const float*)d_in[11];
  const float* bc2 = (const float*)d_in[12];
  float* out = (float*)d_out;

  int N = in_sizes[0] / HDIM;
  int E = in_sizes[1] / 2;
  const int* src = ei;
  const int* dst = ei + E;

  int NB1 = (N + 255) >> 8;
  int G = (E + CHUNK - 1) / CHUNK;
  int M = NB1 * G;

  char* ws = (char*)d_ws;
  size_t off = 0;
  auto alloc = [&](size_t bytes) -> void* {
    void* p = (void*)(ws + off);
    off += (bytes + 511) & ~(size_t)511;
    return p;
  };
  // N+1 rows per state buffer (row N = sentinel, zeroed once in mega1)
  unsigned char* Sa = (unsigned char*)alloc((size_t)(N + 1) * HDIM * 2);
  unsigned char* Sb = Sa + (size_t)(N + 1) * HDIM;
  float* csa  = (float*)alloc((size_t)(N + 2) * 4);
  float* csb  = (float*)alloc((size_t)(N + 2) * 4);
  float* cs_base = (float*)alloc((size_t)N * 4);
  float* dinv = (float*)alloc((size_t)N * 4);
  int2*  rowpe = (int2*)alloc((size_t)(NB1 * 256 + 2) * 8);
  int*   colv = (int*)alloc((size_t)(E + NB1 * 1024 + 1024) * 4);
  unsigned* sp = (unsigned*)alloc((size_t)E * 4);
  float* pooled = (float*)alloc((size_t)GCOUNT * HDIM * 4);
  float* gcnt   = (float*)alloc((size_t)GCOUNT * 4);
  unsigned short* wt_hi[3], *wt_lo[3];
  for (int i = 0; i < 3; i++) {
    wt_hi[i] = (unsigned short*)alloc(HDIM * HDIM * 2);
    wt_lo[i] = (unsigned short*)alloc(HDIM * HDIM * 2);
  }
  int* gcount = (int*)alloc((size_t)(M + 2) * 4);
  int nbM = (M + 1023) / 1024;  // ~299 <= 512 (required by inline bsum scans)
  int* bsum = (int*)alloc((size_t)nbM * 4);

  // 1. mega1
  int pz = (GCOUNT * HDIM + GCOUNT + 255) / 256;
  int psb = (N + 15) / 16;
  mega1<<<192 + pz + G + psb, 256, 0, stream>>>(W0, W1, W2,
      wt_hi[0], wt_lo[0], wt_hi[1], wt_lo[1], wt_hi[2], wt_lo[2],
      pooled, gcnt, pz, dst, E, G, NB1, gcount,
      x, (uint2*)Sa, (uint2*)Sb, csa, csb, cs_base, N);

  // 2. scanA only (bsum correction applied inline by consumers)
  scanA<<<nbM, 1024, 0, stream>>>(gcount, bsum, M);

  // 3-4. scatter + fine CSR (padded, packed sp)
  rs_scatter<<<G, 512, 0, stream>>>(src, dst, gcount, bsum, nbM, E, G, NB1, sp);
  csr_fine<<<NB1, 512, 0, stream>>>(sp, gcount, bsum, nbM, E, G, NB1, rowpe, colv,
      dinv, cs_base, csa, N);

  // 5-7. fused agg+gemm per layer, pool folded into layer 2
  int fusedBlocks = (N + 63) / 64;

  fused_q8<<<fusedBlocks, 256, 0, stream>>>((const uint2*)Sa, csa, dinv, rowpe, colv,
      (const uint4*)wt_hi[0], (const uint4*)wt_lo[0], b0, Sb, csb, N);

  fused_q8<<<fusedBlocks, 256, 0, stream>>>((const uint2*)Sb, csb, dinv, rowpe, colv,
      (const uint4*)wt_hi[1], (const uint4*)wt_lo[1], b1, Sa, csa, N);

  fused_final<<<fusedBlocks, 256, 0, stream>>>((const uint2*)Sa, csa, dinv, rowpe, colv,
      (const uint4*)wt_hi[2], (const uint4*)wt_lo[2], b2, bat, pooled, gcnt, N);

  // 8. classifier
  cls_kernel<<<GCOUNT, HDIM, 0, stream>>>(pooled, gcnt, Wc1, bc1, Wc2, bc2, out);
}